// Round 10
// baseline (202.218 us; speedup 1.0000x reference)
//
#include <hip/hip_runtime.h>
#include <math.h>

#define EPSF 1e-12f

typedef short bf16x8 __attribute__((ext_vector_type(8)));
typedef float f32x4 __attribute__((ext_vector_type(4)));

__device__ __forceinline__ void gload_lds16(const void* g, void* l) {
  __builtin_amdgcn_global_load_lds(
      (const __attribute__((address_space(1))) unsigned int*)g,
      (__attribute__((address_space(3))) unsigned int*)l, 16, 0, 0);
}

__device__ __forceinline__ unsigned short bf16_rne(float f) {
  unsigned int u = __float_as_uint(f);
  u += 0x7fffu + ((u >> 16) & 1u);
  return (unsigned short)(u >> 16);
}

__device__ __forceinline__ float bf16_to_f32(unsigned short h) {
  return __uint_as_float((unsigned int)h << 16);
}

// ---------------- block reduce (256 threads, wave64) ----------------
__device__ __forceinline__ float block_reduce_sum_256(float v) {
#pragma unroll
  for (int o = 32; o > 0; o >>= 1) v += __shfl_down(v, o, 64);
  __shared__ float ws4[4];
  const int lane = threadIdx.x & 63;
  const int w = threadIdx.x >> 6;
  if (lane == 0) ws4[w] = v;
  __syncthreads();
  if (threadIdx.x == 0) ws4[0] = ws4[0] + ws4[1] + ws4[2] + ws4[3];
  __syncthreads();
  return ws4[0];
}

// ---------------- stage 1: src readout (float4, 2 batches/block) ----------------
__global__ __launch_bounds__(256) void k_src_readout(const float* __restrict__ m,
                                                     const int* __restrict__ src_mask,
                                                     unsigned short* __restrict__ srcRb,
                                                     float* __restrict__ ssq) {
  const int tid = threadIdx.x;
  const int sub = tid >> 7, t = tid & 127;
  const int b = blockIdx.x * 2 + sub;
  __shared__ int msk[2][32];
  __shared__ float sinv[2];
  __shared__ float red[4];
  if (t < 32) msk[sub][t] = src_mask[b * 32 + t];
  __syncthreads();
  if (t == 0) {
    float c = 0.f;
    for (int s = 0; s < 32; ++s) c += (float)msk[sub][s];
    sinv[sub] = 1.0f / fmaxf(c, EPSF);
  }
  __syncthreads();
  const float inv = sinv[sub];
  const float4* mb = (const float4*)(m + (size_t)b * (32 * 512)) + t;
  float ax = 0.f, ay = 0.f, az = 0.f, aw = 0.f;
  for (int s = 0; s < 32; ++s) {
    if (msk[sub][s] != 0) {
      float4 v = mb[s * 128];
      ax += v.x; ay += v.y; az += v.z; aw += v.w;
    }
  }
  ushort4 o;
  o.x = bf16_rne(ax * inv);
  o.y = bf16_rne(ay * inv);
  o.z = bf16_rne(az * inv);
  o.w = bf16_rne(aw * inv);
  *(ushort4*)(srcRb + (size_t)b * 512 + t * 4) = o;
  float fx = bf16_to_f32(o.x), fy = bf16_to_f32(o.y);
  float fz = bf16_to_f32(o.z), fw = bf16_to_f32(o.w);
  float s = fx * fx + fy * fy + fz * fz + fw * fw;
#pragma unroll
  for (int oo = 32; oo > 0; oo >>= 1) s += __shfl_down(s, oo, 64);
  if ((tid & 63) == 0) red[tid >> 6] = s;
  __syncthreads();
  if (t == 0) ssq[b] = red[sub * 2] + red[sub * 2 + 1];
}

// ---------------- stage 2: tgt readout via MFMA mask-GEMM -> fragment-order A' ----------------
#define WST 72
__global__ __launch_bounds__(512) void k_tgt_readout_mfma(
    const float* __restrict__ om, const int* __restrict__ tgt_mask,
    unsigned short* __restrict__ Afrag) {
  const int b = blockIdx.x, dq = blockIdx.y, th = blockIdx.z;
  const int d0 = dq * 128, t0 = th * 128;
  __shared__ unsigned short Wb[128 * WST];
  __shared__ unsigned short omT[128 * WST];
  __shared__ float cntp[128 * 4];
  __shared__ float cnt_inv[128];
  const int tid = threadIdx.x;
  const int lane = tid & 63, w = tid >> 6;
  const int* mbase = tgt_mask + (size_t)b * 65536 + (size_t)t0 * 256;

  {
    const int t = tid >> 2, q = tid & 3;
    const int* mp = mbase + t * 256 + q * 64;
    int c = 0;
#pragma unroll
    for (int k = 0; k < 16; ++k) {
      int4 v = *(const int4*)(mp + 4 * k);
      c += v.x + v.y + v.z + v.w;
    }
    cntp[t * 4 + q] = (float)c;
  }
  __syncthreads();
  if (tid < 128) {
    float c = cntp[tid * 4] + cntp[tid * 4 + 1] + cntp[tid * 4 + 2] + cntp[tid * 4 + 3];
    cnt_inv[tid] = 1.0f / fmaxf(c, EPSF);
  }

  f32x4 acc[8];
#pragma unroll
  for (int di = 0; di < 8; ++di) acc[di] = (f32x4){0.f, 0.f, 0.f, 0.f};

  for (int uc = 0; uc < 4; ++uc) {
    const int ub = uc * 64;
    __syncthreads();
    {
      const int t = tid >> 2, ul0 = (tid & 3) * 16;
      const int* mp = mbase + t * 256 + ub + ul0;
      unsigned short* wp = Wb + t * WST + ul0;
#pragma unroll
      for (int k = 0; k < 4; ++k) {
        int4 v = *(const int4*)(mp + 4 * k);
        ushort4 h;
        h.x = v.x ? 0x3F80 : 0;
        h.y = v.y ? 0x3F80 : 0;
        h.z = v.z ? 0x3F80 : 0;
        h.w = v.w ? 0x3F80 : 0;
        *(ushort4*)(wp + 4 * k) = h;
      }
    }
    {
#pragma unroll
      for (int k = 0; k < 4; ++k) {
        const int idx = tid + 512 * k;
        const int u = idx >> 5, dl = (idx & 31) * 4;
        float4 v = *(const float4*)(om + (size_t)b * 131072 + (size_t)(ub + u) * 512 + d0 + dl);
        omT[(dl + 0) * WST + u] = bf16_rne(v.x);
        omT[(dl + 1) * WST + u] = bf16_rne(v.y);
        omT[(dl + 2) * WST + u] = bf16_rne(v.z);
        omT[(dl + 3) * WST + u] = bf16_rne(v.w);
      }
    }
    __syncthreads();
#pragma unroll
    for (int kt2 = 0; kt2 < 2; ++kt2) {
      const int ko = kt2 * 32 + (lane >> 4) * 8;
      bf16x8 wf = *(const bf16x8*)(Wb + (w * 16 + (lane & 15)) * WST + ko);
      bf16x8 of[8];
#pragma unroll
      for (int di = 0; di < 8; ++di)
        of[di] = *(const bf16x8*)(omT + (di * 16 + (lane & 15)) * WST + ko);
#pragma unroll
      for (int di = 0; di < 8; ++di)
        acc[di] = __builtin_amdgcn_mfma_f32_16x16x32_bf16(of[di], wf, acc[di], 0, 0, 0);
    }
  }

  const int tl = w * 16 + (lane & 15);
  const int rT = b * 256 + t0 + tl;
  const float inv = cnt_inv[tl];
#pragma unroll
  for (int di = 0; di < 8; ++di) {
    const int d = d0 + di * 16 + (lane >> 4) * 4;
    ushort4 o;
    o.x = bf16_rne(acc[di][0] * inv);
    o.y = bf16_rne(acc[di][1] * inv);
    o.z = bf16_rne(acc[di][2] * inv);
    o.w = bf16_rne(acc[di][3] * inv);
    const size_t off =
        (((size_t)(rT >> 4) * 16 + (d >> 5)) * 64 + ((d >> 3) & 3) * 16 + (rT & 15)) * 8 + (d & 7);
    *(ushort4*)(Afrag + off) = o;
  }
}

// ---------------- stage 2b: row squared norms from fragment-order A' ----------------
__global__ __launch_bounds__(256) void k_rowsq_frag(const unsigned short* __restrict__ Afrag,
                                                    float* __restrict__ sq) {
  const int r = blockIdx.x;
  const int tid = threadIdx.x;
  const int g = r >> 4, rl = r & 15;
  const int d = 2 * tid;
  const size_t off = ((size_t)((g * 16 + (d >> 5)) * 64 + ((d >> 3) & 3) * 16 + rl)) * 8 + (d & 7);
  ushort2 v = *(const ushort2*)(Afrag + off);
  float fx = bf16_to_f32(v.x), fy = bf16_to_f32(v.y);
  float s = fx * fx + fy * fy;
  s = block_reduce_sum_256(s);
  if (tid == 0) sq[r] = s;
}

// ---------------- stage 3: cross GEMM, compute-twice store-once ----------------
// Shared body: B-stationary 128-col panel in LDS (staged once, 1 barrier), A streamed
// fragment-order, 512x128 tile, 8 row-waves, 32 MFMA/K-step/wave.
// PASS 0: row-sum of sim via j-accumulate + 16-lane xor-butterfly -> psum[ct][row] (1 MB).
// PASS 1: recompute sim, multiply by rsinv[row], nt-store to out. No sim intermediate.
template <int PASS>
__global__ __launch_bounds__(512, 2) void k_cross_pass(
    const unsigned short* __restrict__ Afrag, const unsigned short* __restrict__ B,
    const float* __restrict__ tsq, const float* __restrict__ ssq,
    float* __restrict__ psum, const float* __restrict__ rsinv,
    float* __restrict__ out) {
  __shared__ unsigned short Bs[128 * 512];
  const int tid = threadIdx.x;
  const int lane = tid & 63, w = tid >> 6;
  const int bid = blockIdx.x;
  const int xcd = bid & 7, idx = bid >> 3;
  const int row0 = (xcd * 2 + (idx >> 5)) * 512;
  const int col0 = (idx & 31) * 128;
  const int lr = lane & 15, lkh = lane >> 4;

#pragma unroll
  for (int t = 0; t < 16; ++t) {
    const int c = w * 16 + t;
    const int j = c >> 4, kt = c & 15;
    gload_lds16(B + (size_t)(col0 + j * 16 + lr) * 512 + kt * 32 + lkh * 8,
                Bs + (size_t)c * 512);
  }

  f32x4 acc[4][8];
#pragma unroll
  for (int i = 0; i < 4; ++i)
#pragma unroll
    for (int j = 0; j < 8; ++j) acc[i][j] = (f32x4){0.f, 0.f, 0.f, 0.f};

  __syncthreads();

  const unsigned short* ap = Afrag + ((size_t)(row0 >> 4) + w * 4) * (16 * 64 * 8);
#pragma unroll
  for (int kt = 0; kt < 16; ++kt) {
    bf16x8 af[4], bfr[8];
#pragma unroll
    for (int i = 0; i < 4; ++i)
      af[i] = *(const bf16x8*)(ap + (((size_t)i * 16 + kt) * 64 + lane) * 8);
#pragma unroll
    for (int j = 0; j < 8; ++j)
      bfr[j] = *(const bf16x8*)(Bs + ((j * 16 + kt) * 64 + lane) * 8);
#pragma unroll
    for (int i = 0; i < 4; ++i)
#pragma unroll
      for (int j = 0; j < 8; ++j)
        acc[i][j] = __builtin_amdgcn_mfma_f32_16x16x32_bf16(af[i], bfr[j], acc[i][j], 0, 0, 0);
  }

  // ---- epilogue ----
  // C/D layout: col = col0 + (lane&15) + j*16, row = row0 + w*64 + (lane>>4)*4 + i*16 + r.
  // All 16 lanes of a (lane>>4)-group share the same rows -> butterfly over lane&15.
  const int cbase = col0 + (lane & 15);
  const int rbase = row0 + w * 64 + (lane >> 4) * 4;
  float ss[8];
#pragma unroll
  for (int j = 0; j < 8; ++j) ss[j] = ssq[cbase + j * 16];
#pragma unroll
  for (int i = 0; i < 4; ++i) {
#pragma unroll
    for (int r = 0; r < 4; ++r) {
      const int row = rbase + i * 16 + r;
      const float t2 = tsq[row];
      if (PASS == 0) {
        float s = 0.f;
#pragma unroll
        for (int j = 0; j < 8; ++j) {
          float d2 = t2 + ss[j] - 2.0f * acc[i][j][r];
          s += expf(-sqrtf(fmaxf(d2, EPSF)));
        }
        s += __shfl_xor(s, 1, 64);
        s += __shfl_xor(s, 2, 64);
        s += __shfl_xor(s, 4, 64);
        s += __shfl_xor(s, 8, 64);
        if ((lane & 15) == 0) psum[(size_t)(col0 >> 7) * 8192 + row] = s;
      } else {
        const float rsv = rsinv[row];
        float* op = out + (size_t)row * 4096 + cbase;
#pragma unroll
        for (int j = 0; j < 8; ++j) {
          float d2 = t2 + ss[j] - 2.0f * acc[i][j][r];
          __builtin_nontemporal_store(expf(-sqrtf(fmaxf(d2, EPSF))) * rsv, op + j * 16);
        }
      }
    }
  }
}

// ---------------- stage 3b: reduce psum -> rsinv ----------------
__global__ __launch_bounds__(256) void k_sum_reduce(const float* __restrict__ psum,
                                                    float* __restrict__ rsinv) {
  const int row = blockIdx.x * 256 + threadIdx.x;
  float s = 0.f;
#pragma unroll
  for (int ct = 0; ct < 32; ++ct) s += psum[(size_t)ct * 8192 + row];
  rsinv[row] = 1.0f / fmaxf(s, EPSF);
}

extern "C" void kernel_launch(void* const* d_in, const int* in_sizes, int n_in,
                              void* d_out, int out_size, void* d_ws, size_t ws_size,
                              hipStream_t stream) {
  const float* m = (const float*)d_in[0];        // [4096,32,512]
  const float* om = (const float*)d_in[1];       // [32,256,512]
  const int* src_mask = (const int*)d_in[2];     // [4096,1,32]
  const int* tgt_mask = (const int*)d_in[3];     // [32,256,256]
  float* out = (float*)d_out;                    // [32,256,4096]

  float* ws = (float*)d_ws;
  float* ssq = ws;                                         // 4096 f32
  float* tsq = ssq + 4096;                                 // 8192 f32
  float* rsinv = tsq + 8192;                               // 8192 f32
  float* psum = rsinv + 8192;                              // 32*8192 f32 (1 MB)
  unsigned short* srcRb = (unsigned short*)(psum + 32 * 8192);  // 4096*512 bf16
  unsigned short* Afrag = srcRb + 4096 * 512;                   // 8192*512 bf16 frag-order

  k_src_readout<<<2048, 256, 0, stream>>>(m, src_mask, srcRb, ssq);
  k_tgt_readout_mfma<<<dim3(32, 4, 2), 512, 0, stream>>>(om, tgt_mask, Afrag);
  k_rowsq_frag<<<8192, 256, 0, stream>>>(Afrag, tsq);
  k_cross_pass<0><<<512, 512, 0, stream>>>(Afrag, srcRb, tsq, ssq, psum, rsinv, out);
  k_sum_reduce<<<32, 256, 0, stream>>>(psum, rsinv);
  k_cross_pass<1><<<512, 512, 0, stream>>>(Afrag, srcRb, tsq, ssq, psum, rsinv, out);
}

// Round 11
// 179.393 us; speedup vs baseline: 1.1272x; 1.1272x over previous
//
#include <hip/hip_runtime.h>
#include <math.h>

#define EPSF 1e-12f

typedef short bf16x8 __attribute__((ext_vector_type(8)));
typedef float f32x4 __attribute__((ext_vector_type(4)));

__device__ __forceinline__ void gload_lds16(const void* g, void* l) {
  __builtin_amdgcn_global_load_lds(
      (const __attribute__((address_space(1))) unsigned int*)g,
      (__attribute__((address_space(3))) unsigned int*)l, 16, 0, 0);
}

__device__ __forceinline__ unsigned short bf16_rne(float f) {
  unsigned int u = __float_as_uint(f);
  u += 0x7fffu + ((u >> 16) & 1u);
  return (unsigned short)(u >> 16);
}

__device__ __forceinline__ float bf16_to_f32(unsigned short h) {
  return __uint_as_float((unsigned int)h << 16);
}

// ---------------- block reduce (256 threads, wave64) ----------------
__device__ __forceinline__ float block_reduce_sum_256(float v) {
#pragma unroll
  for (int o = 32; o > 0; o >>= 1) v += __shfl_down(v, o, 64);
  __shared__ float ws4[4];
  const int lane = threadIdx.x & 63;
  const int w = threadIdx.x >> 6;
  if (lane == 0) ws4[w] = v;
  __syncthreads();
  if (threadIdx.x == 0) ws4[0] = ws4[0] + ws4[1] + ws4[2] + ws4[3];
  __syncthreads();
  return ws4[0];
}

// ---------------- stage 1: src readout (float4, 2 batches/block) ----------------
__global__ __launch_bounds__(256) void k_src_readout(const float* __restrict__ m,
                                                     const int* __restrict__ src_mask,
                                                     unsigned short* __restrict__ srcRb,
                                                     float* __restrict__ ssq) {
  const int tid = threadIdx.x;
  const int sub = tid >> 7, t = tid & 127;
  const int b = blockIdx.x * 2 + sub;
  __shared__ int msk[2][32];
  __shared__ float sinv[2];
  __shared__ float red[4];
  if (t < 32) msk[sub][t] = src_mask[b * 32 + t];
  __syncthreads();
  if (t == 0) {
    float c = 0.f;
    for (int s = 0; s < 32; ++s) c += (float)msk[sub][s];
    sinv[sub] = 1.0f / fmaxf(c, EPSF);
  }
  __syncthreads();
  const float inv = sinv[sub];
  const float4* mb = (const float4*)(m + (size_t)b * (32 * 512)) + t;
  float ax = 0.f, ay = 0.f, az = 0.f, aw = 0.f;
  for (int s = 0; s < 32; ++s) {
    if (msk[sub][s] != 0) {
      float4 v = mb[s * 128];
      ax += v.x; ay += v.y; az += v.z; aw += v.w;
    }
  }
  ushort4 o;
  o.x = bf16_rne(ax * inv);
  o.y = bf16_rne(ay * inv);
  o.z = bf16_rne(az * inv);
  o.w = bf16_rne(aw * inv);
  *(ushort4*)(srcRb + (size_t)b * 512 + t * 4) = o;
  float fx = bf16_to_f32(o.x), fy = bf16_to_f32(o.y);
  float fz = bf16_to_f32(o.z), fw = bf16_to_f32(o.w);
  float s = fx * fx + fy * fy + fz * fz + fw * fw;
#pragma unroll
  for (int oo = 32; oo > 0; oo >>= 1) s += __shfl_down(s, oo, 64);
  if ((tid & 63) == 0) red[tid >> 6] = s;
  __syncthreads();
  if (t == 0) ssq[b] = red[sub * 2] + red[sub * 2 + 1];
}

// ---------------- stage 2: tgt readout via MFMA mask-GEMM -> fragment-order A' ----------------
#define WST 72
__global__ __launch_bounds__(512) void k_tgt_readout_mfma(
    const float* __restrict__ om, const int* __restrict__ tgt_mask,
    unsigned short* __restrict__ Afrag) {
  const int b = blockIdx.x, dq = blockIdx.y, th = blockIdx.z;
  const int d0 = dq * 128, t0 = th * 128;
  __shared__ unsigned short Wb[128 * WST];
  __shared__ unsigned short omT[128 * WST];
  __shared__ float cntp[128 * 4];
  __shared__ float cnt_inv[128];
  const int tid = threadIdx.x;
  const int lane = tid & 63, w = tid >> 6;
  const int* mbase = tgt_mask + (size_t)b * 65536 + (size_t)t0 * 256;

  {
    const int t = tid >> 2, q = tid & 3;
    const int* mp = mbase + t * 256 + q * 64;
    int c = 0;
#pragma unroll
    for (int k = 0; k < 16; ++k) {
      int4 v = *(const int4*)(mp + 4 * k);
      c += v.x + v.y + v.z + v.w;
    }
    cntp[t * 4 + q] = (float)c;
  }
  __syncthreads();
  if (tid < 128) {
    float c = cntp[tid * 4] + cntp[tid * 4 + 1] + cntp[tid * 4 + 2] + cntp[tid * 4 + 3];
    cnt_inv[tid] = 1.0f / fmaxf(c, EPSF);
  }

  f32x4 acc[8];
#pragma unroll
  for (int di = 0; di < 8; ++di) acc[di] = (f32x4){0.f, 0.f, 0.f, 0.f};

  for (int uc = 0; uc < 4; ++uc) {
    const int ub = uc * 64;
    __syncthreads();
    {
      const int t = tid >> 2, ul0 = (tid & 3) * 16;
      const int* mp = mbase + t * 256 + ub + ul0;
      unsigned short* wp = Wb + t * WST + ul0;
#pragma unroll
      for (int k = 0; k < 4; ++k) {
        int4 v = *(const int4*)(mp + 4 * k);
        ushort4 h;
        h.x = v.x ? 0x3F80 : 0;
        h.y = v.y ? 0x3F80 : 0;
        h.z = v.z ? 0x3F80 : 0;
        h.w = v.w ? 0x3F80 : 0;
        *(ushort4*)(wp + 4 * k) = h;
      }
    }
    {
#pragma unroll
      for (int k = 0; k < 4; ++k) {
        const int idx = tid + 512 * k;
        const int u = idx >> 5, dl = (idx & 31) * 4;
        float4 v = *(const float4*)(om + (size_t)b * 131072 + (size_t)(ub + u) * 512 + d0 + dl);
        omT[(dl + 0) * WST + u] = bf16_rne(v.x);
        omT[(dl + 1) * WST + u] = bf16_rne(v.y);
        omT[(dl + 2) * WST + u] = bf16_rne(v.z);
        omT[(dl + 3) * WST + u] = bf16_rne(v.w);
      }
    }
    __syncthreads();
#pragma unroll
    for (int kt2 = 0; kt2 < 2; ++kt2) {
      const int ko = kt2 * 32 + (lane >> 4) * 8;
      bf16x8 wf = *(const bf16x8*)(Wb + (w * 16 + (lane & 15)) * WST + ko);
      bf16x8 of[8];
#pragma unroll
      for (int di = 0; di < 8; ++di)
        of[di] = *(const bf16x8*)(omT + (di * 16 + (lane & 15)) * WST + ko);
#pragma unroll
      for (int di = 0; di < 8; ++di)
        acc[di] = __builtin_amdgcn_mfma_f32_16x16x32_bf16(of[di], wf, acc[di], 0, 0, 0);
    }
  }

  const int tl = w * 16 + (lane & 15);
  const int rT = b * 256 + t0 + tl;
  const float inv = cnt_inv[tl];
#pragma unroll
  for (int di = 0; di < 8; ++di) {
    const int d = d0 + di * 16 + (lane >> 4) * 4;
    ushort4 o;
    o.x = bf16_rne(acc[di][0] * inv);
    o.y = bf16_rne(acc[di][1] * inv);
    o.z = bf16_rne(acc[di][2] * inv);
    o.w = bf16_rne(acc[di][3] * inv);
    const size_t off =
        (((size_t)(rT >> 4) * 16 + (d >> 5)) * 64 + ((d >> 3) & 3) * 16 + (rT & 15)) * 8 + (d & 7);
    *(ushort4*)(Afrag + off) = o;
  }
}

// ---------------- stage 2b: row squared norms from fragment-order A' ----------------
__global__ __launch_bounds__(256) void k_rowsq_frag(const unsigned short* __restrict__ Afrag,
                                                    float* __restrict__ sq) {
  const int r = blockIdx.x;
  const int tid = threadIdx.x;
  const int g = r >> 4, rl = r & 15;
  const int d = 2 * tid;
  const size_t off = ((size_t)((g * 16 + (d >> 5)) * 64 + ((d >> 3) & 3) * 16 + rl)) * 8 + (d & 7);
  ushort2 v = *(const ushort2*)(Afrag + off);
  float fx = bf16_to_f32(v.x), fy = bf16_to_f32(v.y);
  float s = fx * fx + fy * fy;
  s = block_reduce_sum_256(s);
  if (tid == 0) sq[r] = s;
}

// ---------------- stage 3: cross GEMM — m97-style: 128x128 tile, 4 waves, 8 KB LDS ----------------
// A read directly from global in fragment order (L2-resident panel, shared by the 32
// consecutive blockIdx.x blocks); B staged per-kt into 8 KB LDS via 2 gload_lds/wave.
// 2 barriers per kt, 16 MFMA/wave between them; ~3 blocks/CU give phase-offset TLP (m114).
__global__ __launch_bounds__(256, 3) void k_cross_mfma(
    const unsigned short* __restrict__ Afrag, const unsigned short* __restrict__ B,
    const float* __restrict__ tsq, const float* __restrict__ ssq,
    float* __restrict__ out) {
  __shared__ unsigned short Bs[8 * 512];  // col-block c (0..7): 64 lanes x 8 shorts
  const int tid = threadIdx.x;
  const int lane = tid & 63, w = tid >> 6;
  const int wm = w >> 1, wn = w & 1;
  const int col0 = blockIdx.x * 128, row0 = blockIdx.y * 128;
  const int lr = lane & 15, lkh = lane >> 4;

  f32x4 acc[4][4];
#pragma unroll
  for (int i = 0; i < 4; ++i)
#pragma unroll
    for (int j = 0; j < 4; ++j) acc[i][j] = (f32x4){0.f, 0.f, 0.f, 0.f};

  const size_t arb0 = (size_t)(row0 >> 4) + wm * 4;  // first A row-block of this wave

  for (int kt = 0; kt < 16; ++kt) {
    const int kb = kt * 32;
    // A fragments direct from global (issue before barriers so VMEM overlaps staging)
    bf16x8 af[4];
#pragma unroll
    for (int i = 0; i < 4; ++i)
      af[i] = *(const bf16x8*)(Afrag + ((arb0 + i) * 16 + kt) * 512 + lane * 8);
    __syncthreads();  // previous iteration's B reads done before overwrite
#pragma unroll
    for (int t = 0; t < 2; ++t) {
      const int c = w * 2 + t;  // col-block 0..7
      gload_lds16(B + (size_t)(col0 + c * 16 + lr) * 512 + kb + lkh * 8,
                  Bs + (size_t)c * 512);
    }
    __syncthreads();  // staged (compiler drains vmcnt before barrier)
    bf16x8 bfr[4];
#pragma unroll
    for (int j = 0; j < 4; ++j)
      bfr[j] = *(const bf16x8*)(Bs + ((wn * 4 + j) * 64 + lane) * 8);
#pragma unroll
    for (int i = 0; i < 4; ++i)
#pragma unroll
      for (int j = 0; j < 4; ++j)
        acc[i][j] = __builtin_amdgcn_mfma_f32_16x16x32_bf16(af[i], bfr[j], acc[i][j], 0, 0, 0);
  }

  // ---- epilogue: d2 = t2 + s2 - 2c ; sim = exp(-sqrt(max(d2,eps))), nt-store ----
  // C/D layout: col = lane&15, row = (lane>>4)*4 + reg  [m89-verified]
  const int cbase = col0 + wn * 64 + (lane & 15);
  const int rbase = row0 + wm * 64 + (lane >> 4) * 4;
  float ss[4];
#pragma unroll
  for (int j = 0; j < 4; ++j) ss[j] = ssq[cbase + j * 16];
#pragma unroll
  for (int i = 0; i < 4; ++i) {
#pragma unroll
    for (int r = 0; r < 4; ++r) {
      const int row = rbase + i * 16 + r;
      const float t2 = tsq[row];
      float* op = out + (size_t)row * 4096 + cbase;
#pragma unroll
      for (int j = 0; j < 4; ++j) {
        float d2 = t2 + ss[j] - 2.0f * acc[i][j][r];
        __builtin_nontemporal_store(expf(-sqrtf(fmaxf(d2, EPSF))), op + j * 16);
      }
    }
  }
}

// ---------------- stage 4: row L1 normalize (in-place f32, nt out-writes) ----------------
__global__ __launch_bounds__(256) void k_norm(float* __restrict__ out) {
  const size_t base = (size_t)blockIdx.x * 4096;
  const int tid = threadIdx.x;
  float4 v[4];
  float s = 0.f;
#pragma unroll
  for (int i = 0; i < 4; ++i) {
    v[i] = *(const float4*)(out + base + (size_t)(tid * 4 + i * 1024));
    s += v[i].x + v[i].y + v[i].z + v[i].w;
  }
  s = block_reduce_sum_256(s);
  const float inv = 1.0f / fmaxf(s, EPSF);
#pragma unroll
  for (int i = 0; i < 4; ++i) {
    f32x4 r;
    r[0] = v[i].x * inv;
    r[1] = v[i].y * inv;
    r[2] = v[i].z * inv;
    r[3] = v[i].w * inv;
    __builtin_nontemporal_store(r, (f32x4*)(out + base + (size_t)(tid * 4 + i * 1024)));
  }
}

extern "C" void kernel_launch(void* const* d_in, const int* in_sizes, int n_in,
                              void* d_out, int out_size, void* d_ws, size_t ws_size,
                              hipStream_t stream) {
  const float* m = (const float*)d_in[0];        // [4096,32,512]
  const float* om = (const float*)d_in[1];       // [32,256,512]
  const int* src_mask = (const int*)d_in[2];     // [4096,1,32]
  const int* tgt_mask = (const int*)d_in[3];     // [32,256,256]
  float* out = (float*)d_out;                    // [32,256,4096]

  float* ws = (float*)d_ws;
  float* ssq = ws;                                         // 4096 f32
  float* tsq = ssq + 4096;                                 // 8192 f32
  unsigned short* srcRb = (unsigned short*)(tsq + 8192);   // 4096*512 bf16 row-major
  unsigned short* Afrag = srcRb + 4096 * 512;              // 8192*512 bf16 fragment-order

  k_src_readout<<<2048, 256, 0, stream>>>(m, src_mask, srcRb, ssq);
  k_tgt_readout_mfma<<<dim3(32, 4, 2), 512, 0, stream>>>(om, tgt_mask, Afrag);
  k_rowsq_frag<<<8192, 256, 0, stream>>>(Afrag, tsq);
  k_cross_mfma<<<dim3(32, 64), 256, 0, stream>>>(Afrag, srcRb, tsq, ssq, out);
  k_norm<<<8192, 256, 0, stream>>>(out);
}

// Round 12
// 166.031 us; speedup vs baseline: 1.2180x; 1.0805x over previous
//
#include <hip/hip_runtime.h>
#include <math.h>

#define EPSF 1e-12f

typedef short bf16x8 __attribute__((ext_vector_type(8)));
typedef float f32x4 __attribute__((ext_vector_type(4)));

__device__ __forceinline__ void gload_lds16(const void* g, void* l) {
  __builtin_amdgcn_global_load_lds(
      (const __attribute__((address_space(1))) unsigned int*)g,
      (__attribute__((address_space(3))) unsigned int*)l, 16, 0, 0);
}

__device__ __forceinline__ unsigned short bf16_rne(float f) {
  unsigned int u = __float_as_uint(f);
  u += 0x7fffu + ((u >> 16) & 1u);
  return (unsigned short)(u >> 16);
}

__device__ __forceinline__ float bf16_to_f32(unsigned short h) {
  return __uint_as_float((unsigned int)h << 16);
}

// ---------------- block reduce (256 threads, wave64) ----------------
__device__ __forceinline__ float block_reduce_sum_256(float v) {
#pragma unroll
  for (int o = 32; o > 0; o >>= 1) v += __shfl_down(v, o, 64);
  __shared__ float ws4[4];
  const int lane = threadIdx.x & 63;
  const int w = threadIdx.x >> 6;
  if (lane == 0) ws4[w] = v;
  __syncthreads();
  if (threadIdx.x == 0) ws4[0] = ws4[0] + ws4[1] + ws4[2] + ws4[3];
  __syncthreads();
  return ws4[0];
}

// ---------------- stage 1: src readout (float4, 2 batches/block) ----------------
__global__ __launch_bounds__(256) void k_src_readout(const float* __restrict__ m,
                                                     const int* __restrict__ src_mask,
                                                     unsigned short* __restrict__ srcRb,
                                                     float* __restrict__ ssq) {
  const int tid = threadIdx.x;
  const int sub = tid >> 7, t = tid & 127;
  const int b = blockIdx.x * 2 + sub;
  __shared__ int msk[2][32];
  __shared__ float sinv[2];
  __shared__ float red[4];
  if (t < 32) msk[sub][t] = src_mask[b * 32 + t];
  __syncthreads();
  if (t == 0) {
    float c = 0.f;
    for (int s = 0; s < 32; ++s) c += (float)msk[sub][s];
    sinv[sub] = 1.0f / fmaxf(c, EPSF);
  }
  __syncthreads();
  const float inv = sinv[sub];
  const float4* mb = (const float4*)(m + (size_t)b * (32 * 512)) + t;
  float ax = 0.f, ay = 0.f, az = 0.f, aw = 0.f;
  for (int s = 0; s < 32; ++s) {
    if (msk[sub][s] != 0) {
      float4 v = mb[s * 128];
      ax += v.x; ay += v.y; az += v.z; aw += v.w;
    }
  }
  ushort4 o;
  o.x = bf16_rne(ax * inv);
  o.y = bf16_rne(ay * inv);
  o.z = bf16_rne(az * inv);
  o.w = bf16_rne(aw * inv);
  *(ushort4*)(srcRb + (size_t)b * 512 + t * 4) = o;
  float fx = bf16_to_f32(o.x), fy = bf16_to_f32(o.y);
  float fz = bf16_to_f32(o.z), fw = bf16_to_f32(o.w);
  float s = fx * fx + fy * fy + fz * fz + fw * fw;
#pragma unroll
  for (int oo = 32; oo > 0; oo >>= 1) s += __shfl_down(s, oo, 64);
  if ((tid & 63) == 0) red[tid >> 6] = s;
  __syncthreads();
  if (t == 0) ssq[b] = red[sub * 2] + red[sub * 2 + 1];
}

// ---------------- stage 2: tgt readout via MFMA mask-GEMM -> fragment-order A' ----------------
#define WST 72
__global__ __launch_bounds__(512) void k_tgt_readout_mfma(
    const float* __restrict__ om, const int* __restrict__ tgt_mask,
    unsigned short* __restrict__ Afrag) {
  const int b = blockIdx.x, dq = blockIdx.y, th = blockIdx.z;
  const int d0 = dq * 128, t0 = th * 128;
  __shared__ unsigned short Wb[128 * WST];
  __shared__ unsigned short omT[128 * WST];
  __shared__ float cntp[128 * 4];
  __shared__ float cnt_inv[128];
  const int tid = threadIdx.x;
  const int lane = tid & 63, w = tid >> 6;
  const int* mbase = tgt_mask + (size_t)b * 65536 + (size_t)t0 * 256;

  {
    const int t = tid >> 2, q = tid & 3;
    const int* mp = mbase + t * 256 + q * 64;
    int c = 0;
#pragma unroll
    for (int k = 0; k < 16; ++k) {
      int4 v = *(const int4*)(mp + 4 * k);
      c += v.x + v.y + v.z + v.w;
    }
    cntp[t * 4 + q] = (float)c;
  }
  __syncthreads();
  if (tid < 128) {
    float c = cntp[tid * 4] + cntp[tid * 4 + 1] + cntp[tid * 4 + 2] + cntp[tid * 4 + 3];
    cnt_inv[tid] = 1.0f / fmaxf(c, EPSF);
  }

  f32x4 acc[8];
#pragma unroll
  for (int di = 0; di < 8; ++di) acc[di] = (f32x4){0.f, 0.f, 0.f, 0.f};

  for (int uc = 0; uc < 4; ++uc) {
    const int ub = uc * 64;
    __syncthreads();
    {
      const int t = tid >> 2, ul0 = (tid & 3) * 16;
      const int* mp = mbase + t * 256 + ub + ul0;
      unsigned short* wp = Wb + t * WST + ul0;
#pragma unroll
      for (int k = 0; k < 4; ++k) {
        int4 v = *(const int4*)(mp + 4 * k);
        ushort4 h;
        h.x = v.x ? 0x3F80 : 0;
        h.y = v.y ? 0x3F80 : 0;
        h.z = v.z ? 0x3F80 : 0;
        h.w = v.w ? 0x3F80 : 0;
        *(ushort4*)(wp + 4 * k) = h;
      }
    }
    {
#pragma unroll
      for (int k = 0; k < 4; ++k) {
        const int idx = tid + 512 * k;
        const int u = idx >> 5, dl = (idx & 31) * 4;
        float4 v = *(const float4*)(om + (size_t)b * 131072 + (size_t)(ub + u) * 512 + d0 + dl);
        omT[(dl + 0) * WST + u] = bf16_rne(v.x);
        omT[(dl + 1) * WST + u] = bf16_rne(v.y);
        omT[(dl + 2) * WST + u] = bf16_rne(v.z);
        omT[(dl + 3) * WST + u] = bf16_rne(v.w);
      }
    }
    __syncthreads();
#pragma unroll
    for (int kt2 = 0; kt2 < 2; ++kt2) {
      const int ko = kt2 * 32 + (lane >> 4) * 8;
      bf16x8 wf = *(const bf16x8*)(Wb + (w * 16 + (lane & 15)) * WST + ko);
      bf16x8 of[8];
#pragma unroll
      for (int di = 0; di < 8; ++di)
        of[di] = *(const bf16x8*)(omT + (di * 16 + (lane & 15)) * WST + ko);
#pragma unroll
      for (int di = 0; di < 8; ++di)
        acc[di] = __builtin_amdgcn_mfma_f32_16x16x32_bf16(of[di], wf, acc[di], 0, 0, 0);
    }
  }

  const int tl = w * 16 + (lane & 15);
  const int rT = b * 256 + t0 + tl;
  const float inv = cnt_inv[tl];
#pragma unroll
  for (int di = 0; di < 8; ++di) {
    const int d = d0 + di * 16 + (lane >> 4) * 4;
    ushort4 o;
    o.x = bf16_rne(acc[di][0] * inv);
    o.y = bf16_rne(acc[di][1] * inv);
    o.z = bf16_rne(acc[di][2] * inv);
    o.w = bf16_rne(acc[di][3] * inv);
    const size_t off =
        (((size_t)(rT >> 4) * 16 + (d >> 5)) * 64 + ((d >> 3) & 3) * 16 + (rT & 15)) * 8 + (d & 7);
    *(ushort4*)(Afrag + off) = o;
  }
}

// ---------------- stage 2b: row squared norms from fragment-order A' ----------------
__global__ __launch_bounds__(256) void k_rowsq_frag(const unsigned short* __restrict__ Afrag,
                                                    float* __restrict__ sq) {
  const int r = blockIdx.x;
  const int tid = threadIdx.x;
  const int g = r >> 4, rl = r & 15;
  const int d = 2 * tid;
  const size_t off = ((size_t)((g * 16 + (d >> 5)) * 64 + ((d >> 3) & 3) * 16 + rl)) * 8 + (d & 7);
  ushort2 v = *(const ushort2*)(Afrag + off);
  float fx = bf16_to_f32(v.x), fy = bf16_to_f32(v.y);
  float s = fx * fx + fy * fy;
  s = block_reduce_sum_256(s);
  if (tid == 0) sq[r] = s;
}

// ---------------- stage 3: cross GEMM — R8 structure + depth-2 A register pipeline ----------------
// B-stationary 128-col panel (128 KB LDS, staged once, 1 barrier), A streamed from
// global in fragment order. Explicit afA/afB double-buffer: loads for kt+1 are issued
// before kt's 32-MFMA cluster, hiding L2 latency under ~620 cycles of MFMA issue.
__global__ __launch_bounds__(512, 2) void k_cross_mfma(
    const unsigned short* __restrict__ Afrag, const unsigned short* __restrict__ B,
    const float* __restrict__ tsq, const float* __restrict__ ssq,
    float* __restrict__ out) {
  __shared__ unsigned short Bs[128 * 512];
  const int tid = threadIdx.x;
  const int lane = tid & 63, w = tid >> 6;
  const int bid = blockIdx.x;
  const int xcd = bid & 7, idx = bid >> 3;
  const int row0 = (xcd * 2 + (idx >> 5)) * 512;
  const int col0 = (idx & 31) * 128;
  const int lr = lane & 15, lkh = lane >> 4;

#pragma unroll
  for (int t = 0; t < 16; ++t) {
    const int c = w * 16 + t;
    const int j = c >> 4, kt = c & 15;
    gload_lds16(B + (size_t)(col0 + j * 16 + lr) * 512 + kt * 32 + lkh * 8,
                Bs + (size_t)c * 512);
  }

  f32x4 acc[4][8];
#pragma unroll
  for (int i = 0; i < 4; ++i)
#pragma unroll
    for (int j = 0; j < 8; ++j) acc[i][j] = (f32x4){0.f, 0.f, 0.f, 0.f};

  const unsigned short* ap = Afrag + ((size_t)(row0 >> 4) + w * 4) * (16 * 64 * 8);
  // Prefetch kt=0 A fragments BEFORE the barrier (overlaps B staging drain)
  bf16x8 afA[4], afB[4];
#pragma unroll
  for (int i = 0; i < 4; ++i)
    afA[i] = *(const bf16x8*)(ap + (((size_t)i * 16 + 0) * 64 + lane) * 8);

  __syncthreads();  // B staged (compiler drains vmcnt before barrier)

#pragma unroll
  for (int kt2 = 0; kt2 < 8; ++kt2) {
    const int k0 = 2 * kt2, k1 = 2 * kt2 + 1;
    // prefetch odd-kt A while even-kt MFMAs issue
#pragma unroll
    for (int i = 0; i < 4; ++i)
      afB[i] = *(const bf16x8*)(ap + (((size_t)i * 16 + k1) * 64 + lane) * 8);
    {
      bf16x8 bfr[8];
#pragma unroll
      for (int j = 0; j < 8; ++j)
        bfr[j] = *(const bf16x8*)(Bs + ((j * 16 + k0) * 64 + lane) * 8);
#pragma unroll
      for (int i = 0; i < 4; ++i)
#pragma unroll
        for (int j = 0; j < 8; ++j)
          acc[i][j] = __builtin_amdgcn_mfma_f32_16x16x32_bf16(afA[i], bfr[j], acc[i][j], 0, 0, 0);
    }
    if (kt2 < 7) {
      // prefetch next even-kt A while odd-kt MFMAs issue
#pragma unroll
      for (int i = 0; i < 4; ++i)
        afA[i] = *(const bf16x8*)(ap + (((size_t)i * 16 + (k0 + 2)) * 64 + lane) * 8);
    }
    {
      bf16x8 bfr[8];
#pragma unroll
      for (int j = 0; j < 8; ++j)
        bfr[j] = *(const bf16x8*)(Bs + ((j * 16 + k1) * 64 + lane) * 8);
#pragma unroll
      for (int i = 0; i < 4; ++i)
#pragma unroll
        for (int j = 0; j < 8; ++j)
          acc[i][j] = __builtin_amdgcn_mfma_f32_16x16x32_bf16(afB[i], bfr[j], acc[i][j], 0, 0, 0);
    }
  }

  const int cbase = col0 + (lane & 15);
  const int rbase = row0 + w * 64 + (lane >> 4) * 4;
  float ss[8];
#pragma unroll
  for (int j = 0; j < 8; ++j) ss[j] = ssq[cbase + j * 16];
#pragma unroll
  for (int i = 0; i < 4; ++i) {
#pragma unroll
    for (int r = 0; r < 4; ++r) {
      const int row = rbase + i * 16 + r;
      const float t2 = tsq[row];
      float* op = out + (size_t)row * 4096 + cbase;
#pragma unroll
      for (int j = 0; j < 8; ++j) {
        float d2 = t2 + ss[j] - 2.0f * acc[i][j][r];
        __builtin_nontemporal_store(expf(-sqrtf(fmaxf(d2, EPSF))), op + j * 16);
      }
    }
  }
}

// ---------------- stage 4: row L1 normalize (in-place f32, nt out-writes) ----------------
__global__ __launch_bounds__(256) void k_norm(float* __restrict__ out) {
  const size_t base = (size_t)blockIdx.x * 4096;
  const int tid = threadIdx.x;
  float4 v[4];
  float s = 0.f;
#pragma unroll
  for (int i = 0; i < 4; ++i) {
    v[i] = *(const float4*)(out + base + (size_t)(tid * 4 + i * 1024));
    s += v[i].x + v[i].y + v[i].z + v[i].w;
  }
  s = block_reduce_sum_256(s);
  const float inv = 1.0f / fmaxf(s, EPSF);
#pragma unroll
  for (int i = 0; i < 4; ++i) {
    f32x4 r;
    r[0] = v[i].x * inv;
    r[1] = v[i].y * inv;
    r[2] = v[i].z * inv;
    r[3] = v[i].w * inv;
    __builtin_nontemporal_store(r, (f32x4*)(out + base + (size_t)(tid * 4 + i * 1024)));
  }
}

extern "C" void kernel_launch(void* const* d_in, const int* in_sizes, int n_in,
                              void* d_out, int out_size, void* d_ws, size_t ws_size,
                              hipStream_t stream) {
  const float* m = (const float*)d_in[0];        // [4096,32,512]
  const float* om = (const float*)d_in[1];       // [32,256,512]
  const int* src_mask = (const int*)d_in[2];     // [4096,1,32]
  const int* tgt_mask = (const int*)d_in[3];     // [32,256,256]
  float* out = (float*)d_out;                    // [32,256,4096]

  float* ws = (float*)d_ws;
  float* ssq = ws;                                         // 4096 f32
  float* tsq = ssq + 4096;                                 // 8192 f32
  unsigned short* srcRb = (unsigned short*)(tsq + 8192);   // 4096*512 bf16 row-major
  unsigned short* Afrag = srcRb + 4096 * 512;              // 8192*512 bf16 fragment-order

  k_src_readout<<<2048, 256, 0, stream>>>(m, src_mask, srcRb, ssq);
  k_tgt_readout_mfma<<<dim3(32, 4, 2), 512, 0, stream>>>(om, tgt_mask, Afrag);
  k_rowsq_frag<<<8192, 256, 0, stream>>>(Afrag, tsq);
  k_cross_mfma<<<512, 512, 0, stream>>>(Afrag, srcRb, tsq, ssq, out);
  k_norm<<<8192, 256, 0, stream>>>(out);
}